// Round 1
// 107.917 us; speedup vs baseline: 1.0542x; 1.0542x over previous
//
#include <hip/hip_runtime.h>

// Bahdanau additive attention: B=8, TE=512, TD=256, H=256, fp32.
//   We = enc @ W_a; Uh = dec @ U_a
//   e[b,j,i] = softmax_i( sum_h V[h]*tanh(We[b,i,h]+Uh[b,j,h]) )
//   c[b,j,h] = sum_i e[b,j,i]*enc[b,i,h]
// d_out = [c (B*TD*H)] ++ [e (B*TD*TE)]
//
// R9 (this round): k_pre rewritten as split-bf16 MFMA GEMM.
//   Old k_pre (fp32 VALU, 64x64 tile, 4x4/thread) was LDS-BW bound at
//   2 B/FMA (>=12us balanced, ~2x with 384-block tail) for 805 MFLOP of math.
//   New: x = hi(bf16) + lo(bf16 residual); C = Ah*Bh + Ah*Bl + Al*Bh via
//   v_mfma_f32_16x16x32_bf16 (dropped lo*lo ~3e-6 abs — negligible).
//   k_tw pre-transposes/splits the 512KB of weights once so A-frags
//   (m=h, n=i) are single ds_read_b128; D layout (col=lane&15,
//   row=(lane>>4)*4+reg) makes the enc epilogue one float4 store per frag
//   directly into the interleaved W4[b][h/4][i][4] layout.
// k_attn unchanged from the 113.6us version (R8: 4-way rcp batching etc).

#define BB 8
#define TE 512
#define TD 256
#define HH 256

#define EXP2F(x) __builtin_amdgcn_exp2f(x)
#define RCPF(x)  __builtin_amdgcn_rcpf(x)
#define KSCALE   2.8853900817779268f    // 2*log2(e)
#define NSC      (-2.8853900817779268f) // -2*log2(e)

typedef __attribute__((ext_vector_type(8))) short short8_t;  // 8 bf16 = 4 VGPR
typedef __attribute__((ext_vector_type(4))) float f32x4;     // MFMA acc

__device__ __forceinline__ unsigned short f2bf(float x) {
    unsigned int u = __float_as_uint(x);
    return (unsigned short)((u + 0x7FFFu + ((u >> 16) & 1u)) >> 16);  // RNE
}
__device__ __forceinline__ float bf2f(unsigned short h) {
    return __uint_as_float(((unsigned int)h) << 16);
}

// ---------------------------------------------------------------------------
// k_tw: one-shot transpose+split of the weights.
//   Wt[s][h][k] (bf16 hi/lo) = W_s[k][h],  s=0: Wa (enc), s=1: Ua (dec).
// 32 blocks x 256 threads, 64x64 tiles via LDS.
// ---------------------------------------------------------------------------
__global__ __launch_bounds__(256) void k_tw(
    const float* __restrict__ Wa, const float* __restrict__ Ua,
    unsigned short* __restrict__ Wth, unsigned short* __restrict__ Wtl)
{
    const int t    = threadIdx.x;
    const int s    = blockIdx.x >> 4;
    const int tile = blockIdx.x & 15;
    const int tk   = (tile >> 2) * 64;
    const int th   = (tile & 3) * 64;
    const float* W = s ? Ua : Wa;

    __shared__ float Ls[64][65];
    const int kr = t >> 4;          // 0..15
    const int hc = (t & 15) * 4;    // 0..60
    #pragma unroll
    for (int r = 0; r < 4; r++) {
        float4 v = *(const float4*)(W + (size_t)(tk + kr + 16 * r) * HH + th + hc);
        Ls[kr + 16 * r][hc + 0] = v.x; Ls[kr + 16 * r][hc + 1] = v.y;
        Ls[kr + 16 * r][hc + 2] = v.z; Ls[kr + 16 * r][hc + 3] = v.w;
    }
    __syncthreads();
    const int hr  = t >> 4;
    const int kc4 = (t & 15) * 4;
    #pragma unroll
    for (int r = 0; r < 4; r++) {
        const int hl = hr + 16 * r;
        float f0 = Ls[kc4 + 0][hl], f1 = Ls[kc4 + 1][hl];
        float f2 = Ls[kc4 + 2][hl], f3 = Ls[kc4 + 3][hl];
        ushort4 hi, lo;
        hi.x = f2bf(f0); lo.x = f2bf(f0 - bf2f(hi.x));
        hi.y = f2bf(f1); lo.y = f2bf(f1 - bf2f(hi.y));
        hi.z = f2bf(f2); lo.z = f2bf(f2 - bf2f(hi.z));
        hi.w = f2bf(f3); lo.w = f2bf(f3 - bf2f(hi.w));
        const size_t o = ((size_t)(s * 256 + th + hl)) * 256 + tk + kc4;
        *(ushort4*)(Wth + o) = hi;
        *(ushort4*)(Wtl + o) = lo;
    }
}

// ---------------------------------------------------------------------------
// k_pre: split-bf16 MFMA GEMM over the concatenated rows X = [enc; dec]
// (M=6144 "i" rows x K=256 x N... computed as D[h][i] so that D-frag rows
// (4 consecutive h per lane) match both output layouts).
// Tile: 64 h x 64 i, 256 threads = 4 waves, wave -> 32x32 (2x2 frags of
// 16x16), K-chunks of 32, reg-prefetch of the next chunk's global loads.
// Fragment layouts (gfx950 v_mfma_f32_16x16x32_bf16):
//   A (h x k): lane holds row = l&15, k = (l>>4)*8 + e  -> b128 from At[h][k]
//   B (k x i): lane holds col = l&15, k = (l>>4)*8 + e  -> b128 from Xs[i][k]
//   D: col(i) = l&15, row(h) = (l>>4)*4 + reg            (m89-verified)
// LDS rows padded to 40 bf16 (80 B) to break the stride-64B bank pattern.
// ---------------------------------------------------------------------------
__global__ __launch_bounds__(256) void k_pre(
    const float* __restrict__ enc, const float* __restrict__ dec,
    const unsigned short* __restrict__ Wth, const unsigned short* __restrict__ Wtl,
    float* __restrict__ W4, float* __restrict__ Uhe)
{
    const int t  = threadIdx.x;
    const int it = blockIdx.x >> 2;       // 0..95  (i-tile)
    const int ht = blockIdx.x & 3;        // 0..3   (h-tile)
    const int i0 = it * 64;
    const int h0 = ht * 64;
    const bool is_enc = (i0 < BB * TE);   // < 4096
    const float* X = is_enc ? (enc + (size_t)i0 * HH)
                            : (dec + (size_t)(i0 - BB * TE) * HH);
    const int s = is_enc ? 0 : 1;
    const unsigned short* Ah = Wth + ((size_t)(s * 256 + h0)) * 256;
    const unsigned short* Al = Wtl + ((size_t)(s * 256 + h0)) * 256;

    __shared__ unsigned short At_h[64][40], At_l[64][40];
    __shared__ unsigned short Xs_h[64][40], Xs_l[64][40];

    // staging: thread -> row sr, k-octet sq
    const int sr = t >> 2;                // 0..63
    const int sq = (t & 3) * 8;           // 0,8,16,24

    // wave / fragment indices
    const int wv = t >> 6, l = t & 63;
    const int wh = (wv & 1) * 32;
    const int wi = (wv >> 1) * 32;
    const int fr = l & 15;
    const int fk = (l >> 4) * 8;
    const int rq = l >> 4;                // D row-quad

    f32x4 acc[2][2];
    #pragma unroll
    for (int a0 = 0; a0 < 2; a0++)
        #pragma unroll
        for (int a1 = 0; a1 < 2; a1++)
            acc[a0][a1] = (f32x4){0.f, 0.f, 0.f, 0.f};

    // prologue: chunk 0 loads
    short8_t aH = *(const short8_t*)(Ah + (size_t)sr * 256 + sq);
    short8_t aL = *(const short8_t*)(Al + (size_t)sr * 256 + sq);
    float4   x0 = *(const float4*)(X + (size_t)sr * HH + sq);
    float4   x1 = *(const float4*)(X + (size_t)sr * HH + sq + 4);

    #pragma unroll
    for (int c = 0; c < 8; c++) {
        // split current X regs into bf16 hi/lo (lo = exact residual, RNE'd)
        short8_t xh, xl;
        {
            unsigned short h;
            h = f2bf(x0.x); xh[0] = (short)h; xl[0] = (short)f2bf(x0.x - bf2f(h));
            h = f2bf(x0.y); xh[1] = (short)h; xl[1] = (short)f2bf(x0.y - bf2f(h));
            h = f2bf(x0.z); xh[2] = (short)h; xl[2] = (short)f2bf(x0.z - bf2f(h));
            h = f2bf(x0.w); xh[3] = (short)h; xl[3] = (short)f2bf(x0.w - bf2f(h));
            h = f2bf(x1.x); xh[4] = (short)h; xl[4] = (short)f2bf(x1.x - bf2f(h));
            h = f2bf(x1.y); xh[5] = (short)h; xl[5] = (short)f2bf(x1.y - bf2f(h));
            h = f2bf(x1.z); xh[6] = (short)h; xl[6] = (short)f2bf(x1.z - bf2f(h));
            h = f2bf(x1.w); xh[7] = (short)h; xl[7] = (short)f2bf(x1.w - bf2f(h));
        }
        __syncthreads();   // prior chunk's readers are done
        *(short8_t*)&At_h[sr][sq] = aH;
        *(short8_t*)&At_l[sr][sq] = aL;
        *(short8_t*)&Xs_h[sr][sq] = xh;
        *(short8_t*)&Xs_l[sr][sq] = xl;
        if (c < 7) {       // prefetch next chunk while this one computes
            const int kc = (c + 1) * 32;
            aH = *(const short8_t*)(Ah + (size_t)sr * 256 + kc + sq);
            aL = *(const short8_t*)(Al + (size_t)sr * 256 + kc + sq);
            x0 = *(const float4*)(X + (size_t)sr * HH + kc + sq);
            x1 = *(const float4*)(X + (size_t)sr * HH + kc + sq + 4);
        }
        __syncthreads();
        #pragma unroll
        for (int fm = 0; fm < 2; fm++) {
            short8_t a_h = *(const short8_t*)&At_h[wh + 16 * fm + fr][fk];
            short8_t a_l = *(const short8_t*)&At_l[wh + 16 * fm + fr][fk];
            #pragma unroll
            for (int fn = 0; fn < 2; fn++) {
                short8_t b_h = *(const short8_t*)&Xs_h[wi + 16 * fn + fr][fk];
                short8_t b_l = *(const short8_t*)&Xs_l[wi + 16 * fn + fr][fk];
                acc[fm][fn] = __builtin_amdgcn_mfma_f32_16x16x32_bf16(a_h, b_h, acc[fm][fn], 0, 0, 0);
                acc[fm][fn] = __builtin_amdgcn_mfma_f32_16x16x32_bf16(a_h, b_l, acc[fm][fn], 0, 0, 0);
                acc[fm][fn] = __builtin_amdgcn_mfma_f32_16x16x32_bf16(a_l, b_h, acc[fm][fn], 0, 0, 0);
            }
        }
    }

    // epilogue: exp2(KSCALE*C); one float4 store per fragment per lane
    #pragma unroll
    for (int fm = 0; fm < 2; fm++) {
        #pragma unroll
        for (int fn = 0; fn < 2; fn++) {
            f32x4 v = acc[fm][fn];
            float4 o;
            o.x = EXP2F(v[0] * KSCALE);
            o.y = EXP2F(v[1] * KSCALE);
            o.z = EXP2F(v[2] * KSCALE);
            o.w = EXP2F(v[3] * KSCALE);
            const int ig = i0 + wi + 16 * fn + fr;      // global concat row
            const int hb = h0 + wh + 16 * fm + rq * 4;  // 4 consecutive h
            if (is_enc) {
                const int b  = ig >> 9;                 // 512 enc rows/batch
                const int ib = ig & 511;
                const int hq = hb >> 2;
                *(float4*)(W4 + (((size_t)b * 64 + hq) * TE + ib) * 4) = o;
            } else {
                const int j = ig - BB * TE;             // global dec row
                *(float4*)(Uhe + (size_t)j * HH + hb) = o;
            }
        }
    }
}

// ---------------------------------------------------------------------------
// k_attn: unchanged (R8). 512 threads = 8 waves; block owns 4 consecutive
// j's of ONE batch, batch = blockIdx&7 (XCD-local). Phase A: wave w ->
// i = 64w+lane, 64 h-quads; per j: 4-way batched reciprocal (14 fma/mul +
// 1 rcp per 4 elements). Softmax: waves 0-3. Phase B: wave w -> i in
// [64w,64w+64), all 4 j; 32 KB LDS reduce.
// ---------------------------------------------------------------------------
__global__ __launch_bounds__(512) void k_attn(
    const float* __restrict__ enc, const float* __restrict__ W4,
    const float* __restrict__ Uhe, const float* __restrict__ Va,
    float* __restrict__ out_c, float* __restrict__ out_e)
{
    const int wv = threadIdx.x >> 6, lane = threadIdx.x & 63;
    const int b   = blockIdx.x & 7;           // XCD-local batch
    const int j0  = (blockIdx.x >> 3) * 4;    // 64 j-groups per batch
    const int jj0 = b * TD + j0;              // block-uniform

    __shared__ float sP[4][TE];      // 8 KB: energies -> probabilities
    __shared__ float sR[8][4][HH];   // 32 KB: phase-B partials

    const int i = (wv << 6) + lane;
    const float* wp = W4 + ((size_t)b * 64 * TE + i) * 4;
    const float* ua = Uhe + (size_t)jj0 * HH;   // block-uniform -> s_load
    const float* va = Va;                        // uniform

    float a0 = 0.f, a1 = 0.f, a2 = 0.f, a3 = 0.f;

    // 4-way batched reciprocal:
    //   sum_k v_k/A_k = (nAB*dCD + nCD*dAB) / (dAB*dCD),
    //   A=1+wx*ux.., dAB=A*B, nAB=vx*B+vy*A, ...
#define QSTEP(ACC, U)                                                     \
    {                                                                     \
        float A_ = fmaf(w4.x, (U).x, 1.f);                                \
        float B_ = fmaf(w4.y, (U).y, 1.f);                                \
        float C_ = fmaf(w4.z, (U).z, 1.f);                                \
        float D_ = fmaf(w4.w, (U).w, 1.f);                                \
        float dAB = A_ * B_, dCD = C_ * D_;                               \
        float nAB = fmaf(v4.x, B_, v4.y * A_);                            \
        float nCD = fmaf(v4.z, D_, v4.w * C_);                            \
        float num = fmaf(nAB, dCD, nCD * dAB);                            \
        ACC = fmaf(num, RCPF(dAB * dCD), ACC);                            \
    }

    #pragma unroll 2
    for (int q = 0; q < 64; q++) {
        float4 w4 = *(const float4*)(wp + (size_t)q * TE * 4);
        float4 v4 = *(const float4*)(va + 4 * q);
        float4 u0 = *(const float4*)(ua + 4 * q);
        float4 u1 = *(const float4*)(ua + HH + 4 * q);
        float4 u2 = *(const float4*)(ua + 2 * HH + 4 * q);
        float4 u3 = *(const float4*)(ua + 3 * HH + 4 * q);
        QSTEP(a0, u0)
        QSTEP(a1, u1)
        QSTEP(a2, u2)
        QSTEP(a3, u3)
    }
#undef QSTEP

    // conflict-free b32 writes (lane-stride 4B), energies in log2 domain
    sP[0][i] = NSC * a0;
    sP[1][i] = NSC * a1;
    sP[2][i] = NSC * a2;
    sP[3][i] = NSC * a3;
    __syncthreads();

    // ---- softmax: wave w in 0..3 handles j0+w ----------------------------
    if (wv < 4) {
        float ev[8];
        float m = -3.0e38f;
        #pragma unroll
        for (int k = 0; k < 8; k++) {
            ev[k] = sP[wv][lane + 64 * k];
            m = fmaxf(m, ev[k]);
        }
        #pragma unroll
        for (int off = 32; off; off >>= 1) m = fmaxf(m, __shfl_xor(m, off, 64));
        float s = 0.f;
        #pragma unroll
        for (int k = 0; k < 8; k++) { ev[k] = EXP2F(ev[k] - m); s += ev[k]; }
        #pragma unroll
        for (int off = 32; off; off >>= 1) s += __shfl_xor(s, off, 64);
        float rs = RCPF(s);
        float* oe = out_e + (size_t)(jj0 + wv) * TE;
        #pragma unroll
        for (int k = 0; k < 8; k++) {
            float p = ev[k] * rs;
            sP[wv][lane + 64 * k] = p;
            oe[lane + 64 * k] = p;
        }
    }
    __syncthreads();

    // ---- Phase B: wave w -> i in [64w, 64w+64), all 4 j ------------------
    const int ib = wv << 6;
    const float* eb = enc + ((size_t)b * TE + ib) * HH + 4 * lane;
    float4 c0 = {0,0,0,0}, c1 = {0,0,0,0}, c2 = {0,0,0,0}, c3 = {0,0,0,0};
    #pragma unroll 2
    for (int k = 0; k < 64; k++) {
        float p0 = sP[0][ib + k];   // uniform broadcasts
        float p1 = sP[1][ib + k];
        float p2 = sP[2][ib + k];
        float p3 = sP[3][ib + k];
        float4 q = *(const float4*)(eb + (size_t)k * HH);
        c0.x = fmaf(p0, q.x, c0.x); c0.y = fmaf(p0, q.y, c0.y);
        c0.z = fmaf(p0, q.z, c0.z); c0.w = fmaf(p0, q.w, c0.w);
        c1.x = fmaf(p1, q.x, c1.x); c1.y = fmaf(p1, q.y, c1.y);
        c1.z = fmaf(p1, q.z, c1.z); c1.w = fmaf(p1, q.w, c1.w);
        c2.x = fmaf(p2, q.x, c2.x); c2.y = fmaf(p2, q.y, c2.y);
        c2.z = fmaf(p2, q.z, c2.z); c2.w = fmaf(p2, q.w, c2.w);
        c3.x = fmaf(p3, q.x, c3.x); c3.y = fmaf(p3, q.y, c3.y);
        c3.z = fmaf(p3, q.z, c3.z); c3.w = fmaf(p3, q.w, c3.w);
    }
    *(float4*)&sR[wv][0][4 * lane] = c0;
    *(float4*)&sR[wv][1][4 * lane] = c1;
    *(float4*)&sR[wv][2][4 * lane] = c2;
    *(float4*)&sR[wv][3][4 * lane] = c3;
    __syncthreads();

    // ---- final reduce: wave w -> (j = w&3, h-half = w>>2) ----------------
    {
        const int jr = wv & 3;
        const int h2 = (wv >> 2) * 128 + 2 * lane;
        float sx = 0.f, sy = 0.f;
        #pragma unroll
        for (int ww = 0; ww < 8; ww++) {
            float2 t = *(const float2*)&sR[ww][jr][h2];
            sx += t.x; sy += t.y;
        }
        float2 o; o.x = sx; o.y = sy;
        *(float2*)(out_c + (size_t)(jj0 + jr) * HH + h2) = o;
    }
}

extern "C" void kernel_launch(void* const* d_in, const int* in_sizes, int n_in,
                              void* d_out, int out_size, void* d_ws, size_t ws_size,
                              hipStream_t stream) {
    const float* enc = (const float*)d_in[0];
    const float* dec = (const float*)d_in[1];
    const float* Wa  = (const float*)d_in[2];
    const float* Ua  = (const float*)d_in[3];
    const float* Va  = (const float*)d_in[4];

    float* W4  = (float*)d_ws;                        // exp2-domain, interleaved
    float* Uhe = W4 + (size_t)BB * HH * TE;           // exp2-domain, B*TD*H
    unsigned short* Wth = (unsigned short*)(Uhe + (size_t)BB * TD * HH); // W^T hi (bf16)
    unsigned short* Wtl = Wth + 2 * 256 * 256;                          // W^T lo (bf16)

    float* out_c = (float*)d_out;                     // [B,TD,H]
    float* out_e = out_c + (size_t)BB * TD * HH;      // [B,TD,TE]

    k_tw<<<32, 256, 0, stream>>>(Wa, Ua, Wth, Wtl);
    k_pre<<<384, 256, 0, stream>>>(enc, dec, Wth, Wtl, W4, Uhe);
    k_attn<<<BB * TD / 4, 512, 0, stream>>>(enc, W4, Uhe, Va, out_c, out_e);
}